// Round 2
// baseline (328.215 us; speedup 1.0000x reference)
//
#include <hip/hip_runtime.h>
#include <hip/hip_bf16.h>

// Joiner: out[b,t,u,v] = tanh(enc[b,t,:] + pred[b,u,:]) . W[v,:] + bias[v]
// B=8 T=512 U=128 D=256 V=128, fp32 in/out. bf16 MFMA (swapped operands:
// A=W rows(v), B=tanh(u)) so C/D lane layout gives float4 stores along v.

constexpr int Bn = 8, Tn = 512, Un = 128, Dn = 256, Vn = 128;

typedef __attribute__((ext_vector_type(8))) short bf16x8;   // 8 bf16 = 4 VGPRs
typedef __attribute__((ext_vector_type(4))) float f32x4;

// fp32 -> bf16 round-to-nearest-even (finite inputs only)
static __device__ __forceinline__ unsigned short f2bf(float f) {
    unsigned int u = __float_as_uint(f);
    unsigned int r = (u + 0x7fffu + ((u >> 16) & 1u)) >> 16;
    return (unsigned short)r;
}

// tanh(x) = 1 - 2/(exp(2x)+1); med3 clamp; 4 VALU + 2 trans
static __device__ __forceinline__ float fast_tanh(float x) {
    float t = __builtin_amdgcn_fmed3f(x, -8.f, 8.f);
    float e = __expf(2.f * t);
    float r = __builtin_amdgcn_rcpf(e + 1.f);
    return __builtin_fmaf(-2.f, r, 1.f);
}

__global__ __launch_bounds__(256) void cvtW_kernel(const float* __restrict__ W,
                                                   unsigned short* __restrict__ Wb) {
    int i = blockIdx.x * 256 + threadIdx.x;          // 32 blocks * 256 * 4 elems = 32768
    float4 v = ((const float4*)W)[i];
    unsigned short r0 = f2bf(v.x), r1 = f2bf(v.y), r2 = f2bf(v.z), r3 = f2bf(v.w);
    unsigned long long packed = (unsigned long long)r0 | ((unsigned long long)r1 << 16) |
                                ((unsigned long long)r2 << 32) | ((unsigned long long)r3 << 48);
    ((unsigned long long*)Wb)[i] = packed;
}

__global__ __launch_bounds__(512, 4) void joiner_kernel(
    const float* __restrict__ enc,         // [B,T,D]
    const float* __restrict__ pred,        // [B,U,D]
    const unsigned short* __restrict__ Wb, // [V,D] bf16 bits
    const float* __restrict__ bias,        // [V]
    float* __restrict__ out)               // [B,T,U,V]
{
    const int bid = blockIdx.x;            // = b*Tn + t
    const int b   = bid >> 9;              // /512
    const int tid = threadIdx.x;
    const int w   = tid >> 6;              // wave 0..7 -> u rows [w*16, w*16+16)
    const int l   = tid & 63;
    const int l16 = l & 15;
    const int lq  = l >> 4;                // 0..3

    const int u = w * 16 + l16;            // this lane's u row (B-operand N index)

    const float* encRow = enc + (size_t)bid * Dn;                       // shared by all 8 waves
    const float* prow   = pred + ((size_t)b * Un + u) * Dn;             // this lane's pred row
    const unsigned short* wrow = Wb + (size_t)l16 * Dn;                 // + n*4096 + d0

    f32x4 acc[8];
#pragma unroll
    for (int n = 0; n < 8; ++n) acc[n] = (f32x4){0.f, 0.f, 0.f, 0.f};

    // prime pred prefetch for kk=0
    float4 cp0 = *(const float4*)(prow + lq * 8);
    float4 cp1 = *(const float4*)(prow + lq * 8 + 4);

#pragma unroll
    for (int kk = 0; kk < 8; ++kk) {
        const int d0 = kk * 32 + lq * 8;

        // W fragments for this kk: issue ALL 8 loads first (latency hidden by tanh)
        bf16x8 bfr[8];
#pragma unroll
        for (int n = 0; n < 8; ++n)
            bfr[n] = *(const bf16x8*)(wrow + n * 16 * Dn + d0);

        // prefetch next kk's pred slice
        float4 np0, np1;
        if (kk < 7) {
            np0 = *(const float4*)(prow + d0 + 32);
            np1 = *(const float4*)(prow + d0 + 36);
        }

        // enc slice (L1-broadcast: all 8 waves share this row)
        float4 e0 = *(const float4*)(encRow + d0);
        float4 e1 = *(const float4*)(encRow + d0 + 4);

        // A... (B-operand) fragment: tanh(enc + pred) -> bf16, in registers
        float ev[8] = {e0.x, e0.y, e0.z, e0.w, e1.x, e1.y, e1.z, e1.w};
        float pv[8] = {cp0.x, cp0.y, cp0.z, cp0.w, cp1.x, cp1.y, cp1.z, cp1.w};
        bf16x8 af;
#pragma unroll
        for (int j = 0; j < 8; ++j)
            af[j] = (short)f2bf(fast_tanh(ev[j] + pv[j]));

#pragma unroll
        for (int n = 0; n < 8; ++n)
            acc[n] = __builtin_amdgcn_mfma_f32_16x16x32_bf16(bfr[n], af, acc[n], 0, 0, 0);

        if (kk < 7) { cp0 = np0; cp1 = np1; }
    }

    // Epilogue: D row = v = n*16 + lq*4 + r (consecutive in r!), col = u = l16-based
    float* outB = out + (size_t)bid * (Un * Vn) + (size_t)u * Vn;
#pragma unroll
    for (int n = 0; n < 8; ++n) {
        float4 bv = ((const float4*)bias)[n * 4 + lq];
        float4 r;
        r.x = acc[n][0] + bv.x;
        r.y = acc[n][1] + bv.y;
        r.z = acc[n][2] + bv.z;
        r.w = acc[n][3] + bv.w;
        *(float4*)(outB + n * 16 + lq * 4) = r;
    }
}

extern "C" void kernel_launch(void* const* d_in, const int* in_sizes, int n_in,
                              void* d_out, int out_size, void* d_ws, size_t ws_size,
                              hipStream_t stream) {
    const float* enc  = (const float*)d_in[0];
    const float* pred = (const float*)d_in[1];
    const float* W    = (const float*)d_in[2];
    const float* bias = (const float*)d_in[3];
    float* out = (float*)d_out;
    unsigned short* Wb = (unsigned short*)d_ws;   // 32768 bf16 = 64 KB

    cvtW_kernel<<<32, 256, 0, stream>>>(W, Wb);
    joiner_kernel<<<Bn * Tn, 512, 0, stream>>>(enc, pred, Wb, bias, out);
}

// Round 4
// 103.288 us; speedup vs baseline: 3.1777x; 3.1777x over previous
//
#include <hip/hip_runtime.h>
#include <hip/hip_bf16.h>

// Joiner: out[b,t,u,v] = tanh(enc[b,t,:] + pred[b,u,:]) . W[v,:] + bias[v]
// B=8 T=512 U=128 D=256 V=128, fp32 in/out.
// Structure: block = (b, 16-t chunk, u-half). pred + W + bias persist in
// registers across the t-loop; per t only enc (1 KB) is read and the 64x256
// tanh tile is shared through XOR-swizzled LDS. Stores dominate (write-bound).

constexpr int Bn = 8, Tn = 512, Un = 128, Dn = 256, Vn = 128;
constexpr int TCHUNK = 16;

typedef __attribute__((ext_vector_type(8))) short bf16x8;   // 8 bf16 = 4 VGPRs
typedef __attribute__((ext_vector_type(4))) float f32x4;

static __device__ __forceinline__ unsigned short f2bf(float f) {
    unsigned int u = __float_as_uint(f);
    return (unsigned short)((u + 0x7fffu + ((u >> 16) & 1u)) >> 16);
}
static __device__ __forceinline__ float bf2f(unsigned short h) {
    return __uint_as_float(((unsigned int)h) << 16);
}
// tanh(x) = 1 - 2/(exp(2x)+1); med3 clamp; 4 VALU + 2 trans
static __device__ __forceinline__ float fast_tanh(float x) {
    float t = __builtin_amdgcn_fmed3f(x, -8.f, 8.f);
    float e = __expf(2.f * t);
    float r = __builtin_amdgcn_rcpf(e + 1.f);
    return __builtin_fmaf(-2.f, r, 1.f);
}

__global__ __launch_bounds__(256) void cvtW_kernel(const float* __restrict__ W,
                                                   unsigned short* __restrict__ Wb) {
    int i = blockIdx.x * 256 + threadIdx.x;          // 32 blocks * 256 * 4 elems = 32768
    float4 v = ((const float4*)W)[i];
    unsigned short r0 = f2bf(v.x), r1 = f2bf(v.y), r2 = f2bf(v.z), r3 = f2bf(v.w);
    unsigned long long packed = (unsigned long long)r0 | ((unsigned long long)r1 << 16) |
                                ((unsigned long long)r2 << 32) | ((unsigned long long)r3 << 48);
    ((unsigned long long*)Wb)[i] = packed;
}

__global__ __launch_bounds__(512, 4) void joiner_kernel(
    const float* __restrict__ enc,         // [B,T,D]
    const float* __restrict__ pred,        // [B,U,D]
    const unsigned short* __restrict__ Wb, // [V,D] bf16 bits
    const float* __restrict__ bias,        // [V]
    float* __restrict__ out)               // [B,T,U,V]
{
    // joint tile: 64 u-rows x 256 d (bf16) as 16B granules, granule ^= (row&7)
    // swizzle -> conflict-free for both the phase-1 writes and phase-2 reads.
    __shared__ unsigned short jointS[64 * 256];   // 32 KB

    const int bid = blockIdx.x;            // (b*32 + tc)*2 + uh
    const int uh  = bid & 1;
    const int tc  = (bid >> 1) & 31;
    const int b   = bid >> 6;
    const int tid = threadIdx.x;
    const int w   = tid >> 6;              // wave 0..7 -> v-tile [w*16, w*16+16)
    const int l16 = tid & 15;
    const int lq  = (tid >> 4) & 3;

    // phase-1 static mapping: thread owns rows {ub, ub+32} x 16 d at d0=db*16
    const int db = tid & 15;               // == l16
    const int ub = tid >> 4;               // 0..31 (== w*4 + lq)

    // ---- persistent state (loaded once per block) ----
    bf16x8 predR[2][2];                    // 2 rows x 16 d, bf16 (16 VGPR)
#pragma unroll
    for (int j = 0; j < 2; ++j) {
        const float* pr = pred + ((size_t)(b * Un + uh * 64 + ub + 32 * j)) * Dn + db * 16;
        float4 a0 = *(const float4*)(pr + 0);
        float4 a1 = *(const float4*)(pr + 4);
        float4 a2 = *(const float4*)(pr + 8);
        float4 a3 = *(const float4*)(pr + 12);
        bf16x8 q0, q1;
        q0[0] = (short)f2bf(a0.x); q0[1] = (short)f2bf(a0.y);
        q0[2] = (short)f2bf(a0.z); q0[3] = (short)f2bf(a0.w);
        q0[4] = (short)f2bf(a1.x); q0[5] = (short)f2bf(a1.y);
        q0[6] = (short)f2bf(a1.z); q0[7] = (short)f2bf(a1.w);
        q1[0] = (short)f2bf(a2.x); q1[1] = (short)f2bf(a2.y);
        q1[2] = (short)f2bf(a2.z); q1[3] = (short)f2bf(a2.w);
        q1[4] = (short)f2bf(a3.x); q1[5] = (short)f2bf(a3.y);
        q1[6] = (short)f2bf(a3.z); q1[7] = (short)f2bf(a3.w);
        predR[j][0] = q0; predR[j][1] = q1;
    }

    bf16x8 wfr[8];                         // W A-frags, 16 v rows x K=256 (32 VGPR)
#pragma unroll
    for (int kk = 0; kk < 8; ++kk)
        wfr[kk] = *(const bf16x8*)(Wb + (size_t)(w * 16 + l16) * Dn + kk * 32 + lq * 8);

    const float4 bv = *(const float4*)(bias + w * 16 + lq * 4);

    const size_t encBase = (size_t)(b * Tn + tc * TCHUNK) * Dn;

    for (int ti = 0; ti < TCHUNK; ++ti) {
        // ---------- phase 1: tanh(enc + pred) -> LDS (each value once) ----------
        const float* er = enc + encBase + (size_t)ti * Dn + db * 16;
        float4 e0 = *(const float4*)(er + 0);
        float4 e1 = *(const float4*)(er + 4);
        float4 e2 = *(const float4*)(er + 8);
        float4 e3 = *(const float4*)(er + 12);
        const float ev[16] = {e0.x, e0.y, e0.z, e0.w, e1.x, e1.y, e1.z, e1.w,
                              e2.x, e2.y, e2.z, e2.w, e3.x, e3.y, e3.z, e3.w};

#pragma unroll
        for (int j = 0; j < 2; ++j) {
            const int r  = ub + 32 * j;
            const int sw = r & 7;
            bf16x8 o0, o1;
#pragma unroll
            for (int i = 0; i < 8; ++i)
                o0[i] = (short)f2bf(fast_tanh(ev[i] + bf2f((unsigned short)predR[j][0][i])));
#pragma unroll
            for (int i = 0; i < 8; ++i)
                o1[i] = (short)f2bf(fast_tanh(ev[8 + i] + bf2f((unsigned short)predR[j][1][i])));
            *(bf16x8*)&jointS[((r * 32) + ((db * 2) ^ sw)) * 8]     = o0;
            *(bf16x8*)&jointS[((r * 32) + ((db * 2 + 1) ^ sw)) * 8] = o1;
        }
        __syncthreads();

        // ---------- phase 2: MFMA (A = W regs, B = joint from LDS) ----------
        f32x4 acc[4];
#pragma unroll
        for (int ut = 0; ut < 4; ++ut) acc[ut] = (f32x4){0.f, 0.f, 0.f, 0.f};

#pragma unroll
        for (int kk = 0; kk < 8; ++kk) {
            bf16x8 bfr[4];
#pragma unroll
            for (int ut = 0; ut < 4; ++ut) {
                const int row = ut * 16 + l16;
                bfr[ut] = *(const bf16x8*)&jointS[((row * 32) + ((kk * 4 + lq) ^ (l16 & 7))) * 8];
            }
#pragma unroll
            for (int ut = 0; ut < 4; ++ut)
                acc[ut] = __builtin_amdgcn_mfma_f32_16x16x32_bf16(wfr[kk], bfr[ut], acc[ut], 0, 0, 0);
        }

        // epilogue: D row = v-in-tile = lq*4+r (float4 along v), col = u-in-tile = l16
        float* ob = out + ((size_t)((b * Tn + tc * TCHUNK + ti) * Un + uh * 64)) * Vn
                        + w * 16 + lq * 4;
#pragma unroll
        for (int ut = 0; ut < 4; ++ut) {
            f32x4 rv;
            rv[0] = acc[ut][0] + bv.x;
            rv[1] = acc[ut][1] + bv.y;
            rv[2] = acc[ut][2] + bv.z;
            rv[3] = acc[ut][3] + bv.w;
            __builtin_nontemporal_store(rv, (f32x4*)(ob + (size_t)(ut * 16 + l16) * Vn));
        }
        __syncthreads();   // jointS safe to overwrite next iteration
    }
}

extern "C" void kernel_launch(void* const* d_in, const int* in_sizes, int n_in,
                              void* d_out, int out_size, void* d_ws, size_t ws_size,
                              hipStream_t stream) {
    const float* enc  = (const float*)d_in[0];
    const float* pred = (const float*)d_in[1];
    const float* W    = (const float*)d_in[2];
    const float* bias = (const float*)d_in[3];
    float* out = (float*)d_out;
    unsigned short* Wb = (unsigned short*)d_ws;   // 32768 bf16 = 64 KB

    cvtW_kernel<<<32, 256, 0, stream>>>(W, Wb);
    // grid = B * (T/TCHUNK) * 2 u-halves = 8 * 32 * 2 = 512 blocks
    joiner_kernel<<<512, 512, 0, stream>>>(enc, pred, Wb, bias, out);
}

// Round 5
// 91.890 us; speedup vs baseline: 3.5718x; 1.1240x over previous
//
#include <hip/hip_runtime.h>
#include <hip/hip_bf16.h>

// Joiner: out[b,t,u,v] = tanh(enc[b,t,:] + pred[b,u,:]) . W[v,:] + bias[v]
// B=8 T=512 U=128 D=256 V=128, fp32 in/out.
// Block = (b, 16-t chunk, u-half of 64). pred + W + bias persist in registers
// across the t-loop. Per t: tanh tile -> XOR-swizzled LDS (double-buffered),
// one raw s_barrier per iter with lgkmcnt-only wait (output stores are NEVER
// drained inside the loop -> continuous write stream; barrier protects LDS
// only). Plain (non-NT) stores so L2 write-combines the 64B granules.

constexpr int Bn = 8, Tn = 512, Un = 128, Dn = 256, Vn = 128;
constexpr int TCHUNK = 16;

typedef __attribute__((ext_vector_type(8))) short bf16x8;   // 8 bf16 = 4 VGPRs
typedef __attribute__((ext_vector_type(4))) float f32x4;

static __device__ __forceinline__ unsigned short f2bf(float f) {
    unsigned int u = __float_as_uint(f);
    return (unsigned short)((u + 0x7fffu + ((u >> 16) & 1u)) >> 16);
}
static __device__ __forceinline__ float bf2f(unsigned short h) {
    return __uint_as_float(((unsigned int)h) << 16);
}
// tanh(x) = 1 - 2/(exp(2x)+1); med3 clamp; 4 VALU + 2 trans
static __device__ __forceinline__ float fast_tanh(float x) {
    float t = __builtin_amdgcn_fmed3f(x, -8.f, 8.f);
    float e = __expf(2.f * t);
    float r = __builtin_amdgcn_rcpf(e + 1.f);
    return __builtin_fmaf(-2.f, r, 1.f);
}

__global__ __launch_bounds__(256) void cvtW_kernel(const float* __restrict__ W,
                                                   unsigned short* __restrict__ Wb) {
    int i = blockIdx.x * 256 + threadIdx.x;          // 32 blocks * 256 * 4 elems = 32768
    float4 v = ((const float4*)W)[i];
    unsigned short r0 = f2bf(v.x), r1 = f2bf(v.y), r2 = f2bf(v.z), r3 = f2bf(v.w);
    unsigned long long packed = (unsigned long long)r0 | ((unsigned long long)r1 << 16) |
                                ((unsigned long long)r2 << 32) | ((unsigned long long)r3 << 48);
    ((unsigned long long*)Wb)[i] = packed;
}

__global__ __launch_bounds__(512, 4) void joiner_kernel(
    const float* __restrict__ enc,         // [B,T,D]
    const float* __restrict__ pred,        // [B,U,D]
    const unsigned short* __restrict__ Wb, // [V,D] bf16 bits
    const float* __restrict__ bias,        // [V]
    float* __restrict__ out)               // [B,T,U,V]
{
    // joint tile: 64 u-rows x 256 d (bf16) as 16B granules, granule ^= (row&7)
    // swizzle (conflict-free writes AND reads, verified 0 conflicts in R2/R4).
    __shared__ unsigned short jointS[2][64 * 256];   // 2 x 32 KB

    const int bid = blockIdx.x;            // (b*32 + tc)*2 + uh
    const int uh  = bid & 1;
    const int tc  = (bid >> 1) & 31;
    const int b   = bid >> 6;
    const int tid = threadIdx.x;
    const int w   = tid >> 6;              // wave 0..7 -> v-tile [w*16, w*16+16)
    const int l16 = tid & 15;
    const int lq  = (tid >> 4) & 3;

    // phase-1 static mapping: thread owns rows {ub, ub+32} x 16 d at d0=db*16
    const int db = tid & 15;
    const int ub = tid >> 4;               // 0..31

    // ---- persistent state (loaded once per block) ----
    bf16x8 predR[2][2];                    // 2 rows x 16 d, bf16 (16 VGPR)
#pragma unroll
    for (int j = 0; j < 2; ++j) {
        const float* pr = pred + ((size_t)(b * Un + uh * 64 + ub + 32 * j)) * Dn + db * 16;
        float4 a0 = *(const float4*)(pr + 0);
        float4 a1 = *(const float4*)(pr + 4);
        float4 a2 = *(const float4*)(pr + 8);
        float4 a3 = *(const float4*)(pr + 12);
        bf16x8 q0, q1;
        q0[0] = (short)f2bf(a0.x); q0[1] = (short)f2bf(a0.y);
        q0[2] = (short)f2bf(a0.z); q0[3] = (short)f2bf(a0.w);
        q0[4] = (short)f2bf(a1.x); q0[5] = (short)f2bf(a1.y);
        q0[6] = (short)f2bf(a1.z); q0[7] = (short)f2bf(a1.w);
        q1[0] = (short)f2bf(a2.x); q1[1] = (short)f2bf(a2.y);
        q1[2] = (short)f2bf(a2.z); q1[3] = (short)f2bf(a2.w);
        q1[4] = (short)f2bf(a3.x); q1[5] = (short)f2bf(a3.y);
        q1[6] = (short)f2bf(a3.z); q1[7] = (short)f2bf(a3.w);
        predR[j][0] = q0; predR[j][1] = q1;
    }

    bf16x8 wfr[8];                         // W A-frags, 16 v rows x K=256 (32 VGPR)
#pragma unroll
    for (int kk = 0; kk < 8; ++kk)
        wfr[kk] = *(const bf16x8*)(Wb + (size_t)(w * 16 + l16) * Dn + kk * 32 + lq * 8);

    const float4 bv = *(const float4*)(bias + w * 16 + lq * 4);

    const size_t encBase = (size_t)(b * Tn + tc * TCHUNK) * Dn;

    // tanh(enc + pred) -> swizzled LDS tile (each value computed exactly once)
    auto write_tile = [&](unsigned short* buf, const float ev[16]) {
#pragma unroll
        for (int j = 0; j < 2; ++j) {
            const int r  = ub + 32 * j;
            const int sw = r & 7;
            bf16x8 o0, o1;
#pragma unroll
            for (int i = 0; i < 8; ++i)
                o0[i] = (short)f2bf(fast_tanh(ev[i] + bf2f((unsigned short)predR[j][0][i])));
#pragma unroll
            for (int i = 0; i < 8; ++i)
                o1[i] = (short)f2bf(fast_tanh(ev[8 + i] + bf2f((unsigned short)predR[j][1][i])));
            *(bf16x8*)&buf[((r * 32) + ((db * 2) ^ sw)) * 8]     = o0;
            *(bf16x8*)&buf[((r * 32) + ((db * 2 + 1) ^ sw)) * 8] = o1;
        }
    };

    // ---- prologue: tile 0 into buf 0 ----
    {
        const float* er = enc + encBase + db * 16;
        float4 a0 = *(const float4*)(er + 0);
        float4 a1 = *(const float4*)(er + 4);
        float4 a2 = *(const float4*)(er + 8);
        float4 a3 = *(const float4*)(er + 12);
        const float ev[16] = {a0.x, a0.y, a0.z, a0.w, a1.x, a1.y, a1.z, a1.w,
                              a2.x, a2.y, a2.z, a2.w, a3.x, a3.y, a3.z, a3.w};
        write_tile(jointS[0], ev);
    }
    asm volatile("s_waitcnt lgkmcnt(0)" ::: "memory");
    __builtin_amdgcn_s_barrier();
    __builtin_amdgcn_sched_barrier(0);

    for (int ti = 0; ti < TCHUNK; ++ti) {
        const unsigned short* cur = jointS[ti & 1];

        // prefetch enc[ti+1] (latency hides under the MFMA phase below)
        float4 p0, p1, p2, p3;
        if (ti + 1 < TCHUNK) {
            const float* er = enc + encBase + (size_t)(ti + 1) * Dn + db * 16;
            p0 = *(const float4*)(er + 0);
            p1 = *(const float4*)(er + 4);
            p2 = *(const float4*)(er + 8);
            p3 = *(const float4*)(er + 12);
        }

        // ---------- MFMA: A = W regs, B = joint tile from LDS ----------
        f32x4 acc[4];
#pragma unroll
        for (int ut = 0; ut < 4; ++ut) acc[ut] = (f32x4){0.f, 0.f, 0.f, 0.f};

#pragma unroll
        for (int kk = 0; kk < 8; ++kk) {
            bf16x8 bfr[4];
#pragma unroll
            for (int ut = 0; ut < 4; ++ut) {
                const int row = ut * 16 + l16;
                bfr[ut] = *(const bf16x8*)&cur[((row * 32) + ((kk * 4 + lq) ^ (l16 & 7))) * 8];
            }
#pragma unroll
            for (int ut = 0; ut < 4; ++ut)
                acc[ut] = __builtin_amdgcn_mfma_f32_16x16x32_bf16(wfr[kk], bfr[ut], acc[ut], 0, 0, 0);
        }

        // ---------- epilogue: bias + plain float4 stores (never drained) ----------
        float* ob = out + ((size_t)((b * Tn + tc * TCHUNK + ti) * Un + uh * 64)) * Vn
                        + w * 16 + lq * 4;
#pragma unroll
        for (int ut = 0; ut < 4; ++ut) {
            f32x4 rv;
            rv[0] = acc[ut][0] + bv.x;
            rv[1] = acc[ut][1] + bv.y;
            rv[2] = acc[ut][2] + bv.z;
            rv[3] = acc[ut][3] + bv.w;
            *(f32x4*)(ob + (size_t)(ut * 16 + l16) * Vn) = rv;
        }

        // ---------- next tanh tile into the other buffer ----------
        if (ti + 1 < TCHUNK) {
            const float ev[16] = {p0.x, p0.y, p0.z, p0.w, p1.x, p1.y, p1.z, p1.w,
                                  p2.x, p2.y, p2.z, p2.w, p3.x, p3.y, p3.z, p3.w};
            write_tile(jointS[(ti + 1) & 1], ev);
            // barrier protects LDS only: wait ds ops, NOT the global stores
            asm volatile("s_waitcnt lgkmcnt(0)" ::: "memory");
            __builtin_amdgcn_s_barrier();
            __builtin_amdgcn_sched_barrier(0);
        }
    }
}

extern "C" void kernel_launch(void* const* d_in, const int* in_sizes, int n_in,
                              void* d_out, int out_size, void* d_ws, size_t ws_size,
                              hipStream_t stream) {
    const float* enc  = (const float*)d_in[0];
    const float* pred = (const float*)d_in[1];
    const float* W    = (const float*)d_in[2];
    const float* bias = (const float*)d_in[3];
    float* out = (float*)d_out;
    unsigned short* Wb = (unsigned short*)d_ws;   // 32768 bf16 = 64 KB

    cvtW_kernel<<<32, 256, 0, stream>>>(W, Wb);
    // grid = B * (T/TCHUNK) * 2 u-halves = 8 * 32 * 2 = 512 blocks
    joiner_kernel<<<512, 512, 0, stream>>>(enc, pred, Wb, bias, out);
}